// Round 11
// baseline (630.002 us; speedup 1.0000x reference)
//
#include <hip/hip_runtime.h>
#include <math.h>

#define NEG_SLOPE 0.2f
#define BN_EPS 1e-5f

typedef short short8 __attribute__((ext_vector_type(8)));
typedef float floatx16 __attribute__((ext_vector_type(16)));

__device__ __forceinline__ float d_leaky(float x){ return x > 0.f ? x : NEG_SLOPE * x; }
__device__ __forceinline__ float d_elu(float x){ return x > 0.f ? x : expm1f(x); }

__device__ __forceinline__ unsigned short f2bf_rne(float f){
  unsigned int u = __float_as_uint(f);
  unsigned int r = (u + 0x7fffu + ((u >> 16) & 1u)) >> 16;
  return (unsigned short)r;
}
__device__ __forceinline__ float bf2f(unsigned short h){ return __uint_as_float((unsigned int)h << 16); }
__device__ __forceinline__ float2 bf2x(unsigned int u){
  float2 r;
  r.x = __uint_as_float(u << 16);
  r.y = __uint_as_float(u & 0xffff0000u);
  return r;
}

__device__ __forceinline__ float wave_sum(float v){
  #pragma unroll
  for (int off = 32; off > 0; off >>= 1) v += __shfl_xor(v, off, 64);
  return v;
}
__device__ __forceinline__ int wave_scan_incl(int v, int lane){
  #pragma unroll
  for (int off = 1; off < 64; off <<= 1){
    int u = __shfl_up(v, off, 64);
    if (lane >= off) v += u;
  }
  return v;
}

// ---------------- CSR build + sentinel init ----------------
__global__ void k_count(const int* __restrict__ dst, int* __restrict__ deg, int E, int N,
                        const float* __restrict__ g2as, const float* __restrict__ g2ad,
                        float* __restrict__ aw2,
                        unsigned short* __restrict__ gath, unsigned short* __restrict__ xh,
                        unsigned short* __restrict__ g1h, unsigned short* __restrict__ m192,
                        int* __restrict__ colv, float* __restrict__ dinv,
                        float* __restrict__ as2ad2){
  int e = blockIdx.x * blockDim.x + threadIdx.x;
  if (e < 64){ aw2[e * 2 + 0] = g2as[e]; aw2[e * 2 + 1] = g2ad[e]; }
  // sentinel node N: zero rows, zero dinv, -inf attention; sentinel edge E -> N
  if (e < 256) gath[(size_t)N * 256 + e] = 0;
  if (e < 128) xh[(size_t)N * 128 + e] = 0;
  if (e < 64)  g1h[(size_t)N * 64 + e] = 0;
  if (e < 192) m192[(size_t)N * 192 + e] = 0;
  if (e == 0){
    colv[E] = N;
    dinv[N] = 0.f;
    as2ad2[2 * N + 0] = -1e30f;
    as2ad2[2 * N + 1] = 0.f;
  }
  if (e < E) atomicAdd(&deg[dst[e]], 1);
}

__global__ __launch_bounds__(256) void k_scan_a(const int* __restrict__ deg, int* __restrict__ bsum, int n){
  int t = threadIdx.x;
  int base = blockIdx.x * 1024 + t * 4;
  int d0=0,d1=0,d2=0,d3=0;
  if (base + 3 < n){ int4 v = *(const int4*)(deg + base); d0=v.x; d1=v.y; d2=v.z; d3=v.w; }
  else {
    if (base   < n) d0 = deg[base];
    if (base+1 < n) d1 = deg[base+1];
    if (base+2 < n) d2 = deg[base+2];
    if (base+3 < n) d3 = deg[base+3];
  }
  int s = d0+d1+d2+d3;
  __shared__ int wsm[4];
  int lane = t & 63, w = t >> 6;
  int incl = wave_scan_incl(s, lane);
  if (lane == 63) wsm[w] = incl;
  __syncthreads();
  if (t == 0) bsum[blockIdx.x] = wsm[0]+wsm[1]+wsm[2]+wsm[3];
}

// scan_c with in-kernel block-prefix (bsum holds raw per-block sums; nb <= 64)
__global__ __launch_bounds__(256) void k_scan_c(const int* __restrict__ deg, const int* __restrict__ bsum,
                                                int* __restrict__ rowp, int* __restrict__ fill,
                                                float* __restrict__ dinv,
                                                float* __restrict__ sdinv, int n, int nb){
  __shared__ int sbx[2];
  int t = threadIdx.x;
  if (t < 64){
    int v = (t < nb) ? bsum[t] : 0;
    int incl = wave_scan_incl(v, t);
    if (t == (int)blockIdx.x) sbx[0] = incl - v;
    if (t == 63) sbx[1] = incl;
  }
  int base = blockIdx.x * 1024 + t * 4;
  int d0=0,d1=0,d2=0,d3=0;
  if (base + 3 < n){ int4 v = *(const int4*)(deg + base); d0=v.x; d1=v.y; d2=v.z; d3=v.w; }
  else {
    if (base   < n) d0 = deg[base];
    if (base+1 < n) d1 = deg[base+1];
    if (base+2 < n) d2 = deg[base+2];
    if (base+3 < n) d3 = deg[base+3];
  }
  int s = d0+d1+d2+d3;
  __shared__ int wsm[4];
  int lane = t & 63, w = t >> 6;
  int incl = wave_scan_incl(s, lane);
  if (lane == 63) wsm[w] = incl;
  __syncthreads();
  int woff = 0;
  #pragma unroll
  for (int j = 0; j < 4; j++) if (j < w) woff += wsm[j];
  int r = sbx[0] + woff + incl - s;
  int dd[4] = {d0,d1,d2,d3};
  #pragma unroll
  for (int j = 0; j < 4; j++){
    int i = base + j;
    if (i < n){
      rowp[i] = r;
      fill[i] = r;
      dinv[i] = rsqrtf((float)(dd[j] + 1));
      sdinv[i] = 1.0f / fmaxf((float)dd[j], 1.0f);
    }
    r += dd[j];
  }
  if (blockIdx.x == 0 && t == 0) rowp[n] = sbx[1];
}

__global__ void k_scatter(const int* __restrict__ src, const int* __restrict__ dst,
                          int* __restrict__ fill,
                          int* __restrict__ colv, int* __restrict__ dstv, int E){
  int e = blockIdx.x * blockDim.x + threadIdx.x;
  if (e < E){
    int d = dst[e];
    int pos = atomicAdd(&fill[d], 1);
    colv[pos] = src[e];
    dstv[pos] = d;
  }
}

// ---------------- weight transpose + split (+ x-split as perm 3) ----------------
struct WDesc { const float* w; unsigned short* th; unsigned short* tl; int K; int Nc; int perm; };
struct WPack { WDesc d[9]; };
__global__ void k_wsplit(WPack p){
  WDesc w = p.d[blockIdx.y];
  int total = w.K * w.Nc;
  if (w.perm == 3){
    for (int i = blockIdx.x * blockDim.x + threadIdx.x; i < total; i += gridDim.x * blockDim.x){
      float v = w.w[i];
      unsigned short h = f2bf_rne(v);
      w.th[i] = h;
      w.tl[i] = f2bf_rne(v - bf2f(h));
    }
    return;
  }
  for (int i = blockIdx.x * blockDim.x + threadIdx.x; i < total; i += gridDim.x * blockDim.x){
    int k = i / w.Nc, n = i % w.Nc;
    int kd = (w.perm == 1) ? ((k & 63) * 4 + (k >> 6)) : k;
    int nd = (w.perm == 2) ? (((n & 63) << 2) | (n >> 6)) : n;
    float v = w.w[i];
    unsigned short h = f2bf_rne(v);
    w.th[(size_t)nd * w.K + kd] = h;
    w.tl[(size_t)nd * w.K + kd] = f2bf_rne(v - bf2f(h));
  }
}

// ---------------- GEMM term helper ----------------
__device__ __forceinline__ void gemm_term(floatx16& acc0, floatx16& acc1,
    const unsigned short* __restrict__ Ah, const unsigned short* __restrict__ Al,
    const unsigned short* __restrict__ Bh, const unsigned short* __restrict__ Bl,
    int K, int lda, int arow, int lr, int ko8){
  const unsigned short* ap  = Ah + (size_t)arow * lda + ko8;
  const unsigned short* alp = Al ? Al + (size_t)arow * lda + ko8 : nullptr;
  const unsigned short* bh0 = Bh + (size_t)lr * K + ko8;
  const unsigned short* bl0 = Bl + (size_t)lr * K + ko8;
  const unsigned short* bh1 = bh0 + (size_t)32 * K;
  const unsigned short* bl1 = bl0 + (size_t)32 * K;
  for (int k0 = 0; k0 < K; k0 += 16){
    short8 a  = *(const short8*)(ap + k0);
    short8 h0 = *(const short8*)(bh0 + k0);
    short8 l0 = *(const short8*)(bl0 + k0);
    short8 h1 = *(const short8*)(bh1 + k0);
    short8 l1 = *(const short8*)(bl1 + k0);
    if (alp){
      short8 a2 = *(const short8*)(alp + k0);
      acc0 = __builtin_amdgcn_mfma_f32_32x32x16_bf16(a2, h0, acc0, 0, 0, 0);
      acc1 = __builtin_amdgcn_mfma_f32_32x32x16_bf16(a2, h1, acc1, 0, 0, 0);
    }
    acc0 = __builtin_amdgcn_mfma_f32_32x32x16_bf16(a, l0, acc0, 0, 0, 0);
    acc0 = __builtin_amdgcn_mfma_f32_32x32x16_bf16(a, h0, acc0, 0, 0, 0);
    acc1 = __builtin_amdgcn_mfma_f32_32x32x16_bf16(a, l1, acc1, 0, 0, 0);
    acc1 = __builtin_amdgcn_mfma_f32_32x32x16_bf16(a, h1, acc1, 0, 0, 0);
  }
}

// ---------------- batched MFMA GEMM ----------------
struct BDesc {
  const unsigned short *A1h, *A1l, *B1h, *B1l;
  const unsigned short *A2h, *A2l, *B2h, *B2l;
  int K1, lda1, K2, lda2;
  const float* bias;
  unsigned short* out; int ldc, coloff, act;
  const float* fc2w; const float* fc2b; float* outf;
};
struct BPack { BDesc d[3]; };
__global__ __launch_bounds__(256) void k_gemm_b(BPack p, int M){
  BDesc d = p.d[blockIdx.y];
  int wave = threadIdx.x >> 6, lane = threadIdx.x & 63;
  int m0 = blockIdx.x * 128 + wave * 32;
  int lr = lane & 31;
  int ko8 = (lane >> 5) * 8;
  floatx16 acc0 = {0,0,0,0,0,0,0,0,0,0,0,0,0,0,0,0};
  floatx16 acc1 = {0,0,0,0,0,0,0,0,0,0,0,0,0,0,0,0};
  int arow = m0 + lr; if (arow >= M) arow = M - 1;
  gemm_term(acc0, acc1, d.A1h, d.A1l, d.B1h, d.B1l, d.K1, d.lda1, arow, lr, ko8);
  if (d.K2) gemm_term(acc0, acc1, d.A2h, d.A2l, d.B2h, d.B2l, d.K2, d.lda2, arow, lr, ko8);
  int col0 = lr, col1 = lr + 32;
  float bias0 = d.bias ? d.bias[col0] : 0.f;
  float bias1 = d.bias ? d.bias[col1] : 0.f;
  float w00 = 0.f, w01 = 0.f, w10 = 0.f, w11 = 0.f, fb0 = 0.f, fb1 = 0.f;
  if (d.fc2w){
    w00 = d.fc2w[col0 * 2 + 0]; w01 = d.fc2w[col0 * 2 + 1];
    w10 = d.fc2w[col1 * 2 + 0]; w11 = d.fc2w[col1 * 2 + 1];
    if (d.fc2b){ fb0 = d.fc2b[0]; fb1 = d.fc2b[1]; }
  }
  int rbase = m0 + 4 * (lane >> 5);
  #pragma unroll
  for (int reg = 0; reg < 16; reg++){
    int row = rbase + (reg & 3) + 8 * (reg >> 2);
    float v0 = acc0[reg] + bias0;
    float v1 = acc1[reg] + bias1;
    if (d.act){ v0 = fmaxf(v0, 0.f); v1 = fmaxf(v1, 0.f); }
    if (d.out && row < M){
      d.out[(size_t)row * d.ldc + d.coloff + col0] = f2bf_rne(v0);
      d.out[(size_t)row * d.ldc + d.coloff + col1] = f2bf_rne(v1);
    }
    if (d.fc2w){
      float p0 = v0 * w00 + v1 * w10;
      float p1 = v0 * w01 + v1 * w11;
      #pragma unroll
      for (int off = 16; off > 0; off >>= 1){
        p0 += __shfl_xor(p0, off, 64);
        p1 += __shfl_xor(p1, off, 64);
      }
      if ((lane & 31) == 0 && row < M){
        d.outf[(size_t)row * 2 + 0] = p0 + fb0;
        d.outf[(size_t)row * 2 + 1] = p1 + fb1;
      }
    }
  }
}

// ---------------- GEMM320 ----------------
__global__ __launch_bounds__(256) void k_gemm320(
    const unsigned short* __restrict__ Ah, const unsigned short* __restrict__ Al,
    const unsigned short* __restrict__ Bh, const unsigned short* __restrict__ Bl,
    unsigned short* __restrict__ C1, unsigned short* __restrict__ C2, int M)
{
  const int K = 128;
  int wave = threadIdx.x >> 6, lane = threadIdx.x & 63;
  int m0 = blockIdx.x * 128 + wave * 32;
  int n0 = blockIdx.y * 64;
  int lr = lane & 31;
  int ko8 = (lane >> 5) * 8;
  floatx16 acc0 = {0,0,0,0,0,0,0,0,0,0,0,0,0,0,0,0};
  floatx16 acc1 = {0,0,0,0,0,0,0,0,0,0,0,0,0,0,0,0};
  int arow = m0 + lr; if (arow >= M) arow = M - 1;
  const unsigned short* ap_h = Ah + (size_t)arow * K + ko8;
  const unsigned short* ap_l = Al + (size_t)arow * K + ko8;
  const unsigned short* bp_h0 = Bh + (size_t)(n0 + lr) * K + ko8;
  const unsigned short* bp_l0 = Bl + (size_t)(n0 + lr) * K + ko8;
  const unsigned short* bp_h1 = bp_h0 + (size_t)32 * K;
  const unsigned short* bp_l1 = bp_l0 + (size_t)32 * K;
  for (int k0 = 0; k0 < K; k0 += 16){
    short8 a_h  = *(const short8*)(ap_h + k0);
    short8 a_l  = *(const short8*)(ap_l + k0);
    short8 b_h0 = *(const short8*)(bp_h0 + k0);
    short8 b_l0 = *(const short8*)(bp_l0 + k0);
    short8 b_h1 = *(const short8*)(bp_h1 + k0);
    short8 b_l1 = *(const short8*)(bp_l1 + k0);
    acc0 = __builtin_amdgcn_mfma_f32_32x32x16_bf16(a_l, b_h0, acc0, 0, 0, 0);
    acc0 = __builtin_amdgcn_mfma_f32_32x32x16_bf16(a_h, b_l0, acc0, 0, 0, 0);
    acc0 = __builtin_amdgcn_mfma_f32_32x32x16_bf16(a_h, b_h0, acc0, 0, 0, 0);
    acc1 = __builtin_amdgcn_mfma_f32_32x32x16_bf16(a_l, b_h1, acc1, 0, 0, 0);
    acc1 = __builtin_amdgcn_mfma_f32_32x32x16_bf16(a_h, b_l1, acc1, 0, 0, 0);
    acc1 = __builtin_amdgcn_mfma_f32_32x32x16_bf16(a_h, b_h1, acc1, 0, 0, 0);
  }
  int col0 = n0 + lr, col1 = col0 + 32;
  unsigned short* Cp; int ld, c0, c1;
  if (col0 >= 256){ Cp = C2; ld = 64; c0 = col0 - 256; c1 = col1 - 256; }
  else { Cp = C1; ld = 256; c0 = col0; c1 = col1; }
  int rbase = m0 + 4 * (lane >> 5);
  #pragma unroll
  for (int reg = 0; reg < 16; reg++){
    int row = rbase + (reg & 3) + 8 * (reg >> 2);
    if (row >= M) continue;
    Cp[(size_t)row * ld + c0] = f2bf_rne(acc0[reg]);
    Cp[(size_t)row * ld + c1] = f2bf_rne(acc1[reg]);
  }
}

// ---------------- GAT1 attention coeffs ----------------
__global__ __launch_bounds__(256) void k_gat_attn4(
    const unsigned short* __restrict__ h, const float* __restrict__ asrc,
    const float* __restrict__ adst, float* __restrict__ a_s, float* __restrict__ a_d, int n){
  int node = blockIdx.x * 4 + (threadIdx.x >> 6);
  int c = threadIdx.x & 63;
  if (node >= n) return;
  uint2 u = *(const uint2*)(h + (size_t)node * 256 + c * 4);
  float2 p0 = bf2x(u.x), p1 = bf2x(u.y);
  float s0 = wave_sum(p0.x * asrc[c]);
  float s1 = wave_sum(p0.y * asrc[64 + c]);
  float s2 = wave_sum(p1.x * asrc[128 + c]);
  float s3 = wave_sum(p1.y * asrc[192 + c]);
  float d0 = wave_sum(p0.x * adst[c]);
  float d1 = wave_sum(p0.y * adst[64 + c]);
  float d2 = wave_sum(p1.x * adst[128 + c]);
  float d3 = wave_sum(p1.y * adst[192 + c]);
  if (c == 0){
    *(float4*)(a_s + (size_t)node * 4) = make_float4(s0, s1, s2, s3);
    *(float4*)(a_d + (size_t)node * 4) = make_float4(d0, d1, d2, d3);
  }
}

// ---------------- per-edge softmax numerators (layer 1, packed bf16) ----------------
__global__ void k_edge_w4(const int* __restrict__ colv, const int* __restrict__ dstv,
                          const float* __restrict__ a_s, const float* __restrict__ a_d,
                          unsigned short* __restrict__ w4b, int E){
  int i = blockIdx.x * blockDim.x + threadIdx.x;
  if (i == 0){
    // sentinel edge slot E: zero weights
    *(uint2*)(w4b + (size_t)E * 4) = make_uint2(0u, 0u);
  }
  if (i >= E) return;
  float4 s4 = *(const float4*)(a_s + (size_t)colv[i] * 4);
  float4 d4 = *(const float4*)(a_d + (size_t)dstv[i] * 4);
  float w0 = __expf(d_leaky(s4.x + d4.x));
  float w1 = __expf(d_leaky(s4.y + d4.y));
  float w2 = __expf(d_leaky(s4.z + d4.z));
  float w3 = __expf(d_leaky(s4.w + d4.w));
  uint2 q;
  q.x = (unsigned int)f2bf_rne(w0) | ((unsigned int)f2bf_rne(w1) << 16);
  q.y = (unsigned int)f2bf_rne(w2) | ((unsigned int)f2bf_rne(w3) << 16);
  *(uint2*)(w4b + (size_t)i * 4) = q;
}

// ---------------- L1AGG: fused GAT1 + GCN1 + SAGE-x aggregation, batch 16, sentinel ----------------
__global__ __launch_bounds__(256) void k_l1agg(
    const unsigned short* __restrict__ gath, const unsigned short* __restrict__ xh,
    const unsigned short* __restrict__ g1h,
    const int* __restrict__ rowp, const int* __restrict__ colv,
    const unsigned short* __restrict__ w4b,
    const float* __restrict__ a_s, const float* __restrict__ a_d,
    const float* __restrict__ gat1_b, const float* __restrict__ gcn1_b,
    const float* __restrict__ dinv, const float* __restrict__ sdinv,
    unsigned short* __restrict__ oh, unsigned short* __restrict__ g2h,
    unsigned short* __restrict__ aggXh, int n, int Esent)
{
  int node = blockIdx.x * 4 + (threadIdx.x >> 6);
  int c = threadIdx.x & 63;
  if (node >= n) return;
  float4 asn = *(const float4*)(a_s + (size_t)node * 4);
  float4 adn = *(const float4*)(a_d + (size_t)node * 4);
  float ws0 = __expf(d_leaky(asn.x + adn.x));
  float ws1 = __expf(d_leaky(asn.y + adn.y));
  float ws2 = __expf(d_leaky(asn.z + adn.z));
  float ws3 = __expf(d_leaky(asn.w + adn.w));
  uint2 su = *(const uint2*)(gath + (size_t)node * 256 + c * 4);
  float2 sp0 = bf2x(su.x), sp1 = bf2x(su.y);
  float den0 = ws0, den1 = ws1, den2 = ws2, den3 = ws3;
  float acc0 = ws0 * sp0.x, acc1 = ws1 * sp0.y, acc2 = ws2 * sp1.x, acc3 = ws3 * sp1.y;
  float di = dinv[node];
  float gacc = di * bf2f(g1h[(size_t)node * 64 + c]);
  float sx0 = 0.f, sx1 = 0.f;
  int b = rowp[node], e = rowp[node + 1];
  for (int i = b; i < e; i += 16){
    int s[16];
    #pragma unroll
    for (int j = 0; j < 16; j++){
      int t = i + j;
      s[j] = (t < e) ? t : Esent;     // sentinel edge slot
    }
    uint2 wq[16];
    #pragma unroll
    for (int j = 0; j < 16; j++) wq[j] = *(const uint2*)(w4b + (size_t)s[j] * 4);
    #pragma unroll
    for (int j = 0; j < 16; j++) s[j] = colv[s[j]];   // now source node (or sentinel node)
    uint2 hv[16];
    #pragma unroll
    for (int j = 0; j < 16; j++) hv[j] = *(const uint2*)(gath + (size_t)s[j] * 256 + c * 4);
    unsigned int hx[16];
    #pragma unroll
    for (int j = 0; j < 16; j++) hx[j] = *(const unsigned int*)(xh + (size_t)s[j] * 128 + c * 2);
    unsigned short hg[16];
    #pragma unroll
    for (int j = 0; j < 16; j++) hg[j] = g1h[(size_t)s[j] * 64 + c];
    float wd[16];
    #pragma unroll
    for (int j = 0; j < 16; j++) wd[j] = dinv[s[j]];
    #pragma unroll
    for (int j = 0; j < 16; j++){
      float2 w01 = bf2x(wq[j].x), w23 = bf2x(wq[j].y);
      float2 a = bf2x(hv[j].x), bb = bf2x(hv[j].y);
      den0 += w01.x; den1 += w01.y; den2 += w23.x; den3 += w23.y;
      acc0 += w01.x * a.x;  acc1 += w01.y * a.y;
      acc2 += w23.x * bb.x; acc3 += w23.y * bb.y;
      gacc += wd[j] * bf2f(hg[j]);
      float2 p = bf2x(hx[j]);
      sx0 += p.x; sx1 += p.y;
    }
  }
  float v0 = d_elu(acc0 / (den0 + 1e-16f) + gat1_b[c]);
  float v1 = d_elu(acc1 / (den1 + 1e-16f) + gat1_b[64 + c]);
  float v2 = d_elu(acc2 / (den2 + 1e-16f) + gat1_b[128 + c]);
  float v3 = d_elu(acc3 / (den3 + 1e-16f) + gat1_b[192 + c]);
  uint2 ohv;
  ohv.x = (unsigned int)f2bf_rne(v0) | ((unsigned int)f2bf_rne(v1) << 16);
  ohv.y = (unsigned int)f2bf_rne(v2) | ((unsigned int)f2bf_rne(v3) << 16);
  *(uint2*)(oh + (size_t)node * 256 + c * 4) = ohv;
  g2h[(size_t)node * 64 + c] = f2bf_rne(fmaxf(di * gacc + gcn1_b[c], 0.f));
  float sd = sdinv[node];
  *(unsigned int*)(aggXh + (size_t)node * 128 + c * 2) =
      (unsigned int)f2bf_rne(sx0 * sd) | ((unsigned int)f2bf_rne(sx1 * sd) << 16);
}

// ---------------- F2: fused GAT2 + GCN2 + SAGE-s1 aggregation, batch 8, sentinel ----------------
__global__ __launch_bounds__(256) void k_f2(
    const unsigned short* __restrict__ m192,
    const int* __restrict__ rowp, const int* __restrict__ colv,
    const float* __restrict__ as2ad2,
    const float* __restrict__ dinv, const float* __restrict__ sdinv,
    const float* __restrict__ gat2_b, const float* __restrict__ gcn2_b,
    unsigned short* __restrict__ cat, unsigned short* __restrict__ aggSh,
    int n, int Esent){
  int node = blockIdx.x * 4 + (threadIdx.x >> 6);
  int c = threadIdx.x & 63;
  if (node >= n) return;
  float di = dinv[node];
  const unsigned short* srow = m192 + (size_t)node * 192;
  float adn = as2ad2[node * 2 + 1];
  float tden = __expf(d_leaky(as2ad2[node * 2 + 0] + adn));
  float tacc = tden * bf2f(srow[c]);
  float gacc = di * bf2f(srow[64 + c]);
  float sacc = 0.f;
  int b = rowp[node], e = rowp[node + 1];
  for (int i = b; i < e; i += 8){
    int s[8];
    #pragma unroll
    for (int j = 0; j < 8; j++){
      int t = i + j;
      s[j] = colv[(t < e) ? t : Esent];
    }
    float w[8];
    #pragma unroll
    for (int j = 0; j < 8; j++) w[j] = __expf(d_leaky(as2ad2[(size_t)s[j] * 2] + adn));
    unsigned short ht[8], hg[8], hs[8];
    #pragma unroll
    for (int j = 0; j < 8; j++){
      const unsigned short* r = m192 + (size_t)s[j] * 192;
      ht[j] = r[c]; hg[j] = r[64 + c]; hs[j] = r[128 + c];
    }
    float wd[8];
    #pragma unroll
    for (int j = 0; j < 8; j++) wd[j] = dinv[s[j]];
    #pragma unroll
    for (int j = 0; j < 8; j++){
      tden += w[j]; tacc += w[j] * bf2f(ht[j]);
      gacc += wd[j] * bf2f(hg[j]);
      sacc += bf2f(hs[j]);
    }
  }
  cat[(size_t)node * 192 + 64 + c] = f2bf_rne(d_elu(tacc / (tden + 1e-16f) + gat2_b[c]));
  cat[(size_t)node * 192 + c] = f2bf_rne(fmaxf(di * gacc + gcn2_b[c], 0.f));
  aggSh[(size_t)node * 64 + c] = f2bf_rne(sacc * sdinv[node]);
}

// ---------------- BN stats + last-block BN-fold into fc1 weights ----------------
__global__ __launch_bounds__(256) void k_bn_stats_fold(
    const unsigned short* __restrict__ x,
    float* __restrict__ bnGCN, float* __restrict__ bnGAT, float* __restrict__ bnSAGE,
    const float* __restrict__ gg, const float* __restrict__ gb,
    const float* __restrict__ ag, const float* __restrict__ ab,
    const float* __restrict__ sg, const float* __restrict__ sb,
    const float* __restrict__ w, const float* __restrict__ wb, float nf,
    unsigned short* __restrict__ fwh, unsigned short* __restrict__ fwl, float* __restrict__ fb,
    int* __restrict__ done, int nblocks, int n)
{
  int seg = blockIdx.y;
  float* sums = (seg == 0) ? bnGCN : (seg == 1) ? bnGAT : bnSAGE;
  int co = seg * 64;
  int c = threadIdx.x & 63;
  int rl = threadIdx.x >> 6;
  float s = 0.f, q = 0.f;
  for (int r = blockIdx.x * 4 + rl; r < n; r += gridDim.x * 4){
    float v = bf2f(x[(size_t)r * 192 + co + c]);
    s += v; q += v * v;
  }
  __shared__ float ls[4][64], lq[4][64];
  ls[rl][c] = s; lq[rl][c] = q;
  __syncthreads();
  if (rl == 0){
    s = ls[0][c] + ls[1][c] + ls[2][c] + ls[3][c];
    q = lq[0][c] + lq[1][c] + lq[2][c] + lq[3][c];
    atomicAdd(&sums[c], s);
    atomicAdd(&sums[64 + c], q);
  }
  __syncthreads();
  __shared__ int lastflag;
  if (threadIdx.x == 0){
    __threadfence();
    int old = atomicAdd(done, 1);
    lastflag = (old == nblocks - 1);
  }
  __syncthreads();
  if (!lastflag) return;
  __threadfence();
  __shared__ float sbn[3][128];
  for (int i = threadIdx.x; i < 384; i += 256){
    float* p = (i < 128) ? bnGCN : (i < 256) ? bnGAT : bnSAGE;
    sbn[i >> 7][i & 127] = atomicAdd(&p[i & 127], 0.0f);
  }
  __syncthreads();
  int tid = threadIdx.x;
  auto st = [&](int c2, float& sc, float& tc){
    int cc = c2 & 63;
    int sg2 = c2 >> 6;
    const float *g, *b;
    if (sg2 == 0){ g = gg; b = gb; }
    else if (sg2 == 1){ g = ag; b = ab; }
    else { g = sg; b = sb; }
    float m = sbn[sg2][cc] / nf;
    float var = sbn[sg2][64 + cc] / nf - m * m;
    float inv = rsqrtf(var + BN_EPS);
    sc = inv * g[cc];
    tc = b[cc] - m * inv * g[cc];
  };
  if (tid < 64){
    float acc = wb[tid];
    for (int c2 = 0; c2 < 192; c2++){
      float sc, tc; st(c2, sc, tc);
      acc += tc * w[c2 * 64 + tid];
    }
    fb[tid] = acc;
  }
  for (int i = tid; i < 192 * 64; i += 256){
    int c2 = i >> 6, nn = i & 63;
    float sc, tc; st(c2, sc, tc);
    float v = sc * w[i];
    unsigned short hh = f2bf_rne(v);
    fwh[nn * 192 + c2] = hh;
    fwl[nn * 192 + c2] = f2bf_rne(v - bf2f(hh));
  }
}

extern "C" void kernel_launch(void* const* d_in, const int* in_sizes, int n_in,
                              void* d_out, int out_size, void* d_ws, size_t ws_size,
                              hipStream_t stream){
  (void)n_in; (void)out_size; (void)ws_size;
  const float* x        = (const float*)d_in[0];
  const int*   ei       = (const int*)  d_in[1];
  const float* gcn1_w   = (const float*)d_in[2];
  const float* gcn1_b   = (const float*)d_in[3];
  const float* gcn2_w   = (const float*)d_in[4];
  const float* gcn2_b   = (const float*)d_in[5];
  const float* gat1_w   = (const float*)d_in[6];
  const float* gat1_as  = (const float*)d_in[7];
  const float* gat1_ad  = (const float*)d_in[8];
  const float* gat1_b   = (const float*)d_in[9];
  const float* gat2_w   = (const float*)d_in[10];
  const float* gat2_as  = (const float*)d_in[11];
  const float* gat2_ad  = (const float*)d_in[12];
  const float* gat2_b   = (const float*)d_in[13];
  const float* sage1_wl = (const float*)d_in[14];
  const float* sage1_bl = (const float*)d_in[15];
  const float* sage1_wr = (const float*)d_in[16];
  const float* sage2_wl = (const float*)d_in[17];
  const float* sage2_bl = (const float*)d_in[18];
  const float* sage2_wr = (const float*)d_in[19];
  const float* bn_gcn_g = (const float*)d_in[20];
  const float* bn_gcn_b = (const float*)d_in[21];
  const float* bn_gat_g = (const float*)d_in[22];
  const float* bn_gat_b = (const float*)d_in[23];
  const float* bn_sage_g= (const float*)d_in[24];
  const float* bn_sage_b= (const float*)d_in[25];
  const float* fc1_w    = (const float*)d_in[26];
  const float* fc1_b    = (const float*)d_in[27];
  const float* fc2_w    = (const float*)d_in[28];
  const float* fc2_b    = (const float*)d_in[29];
  float* out = (float*)d_out;

  const int N = in_sizes[0] / 128;
  const int E = in_sizes[1] / 2;
  const int* src = ei;
  const int* dst = ei + E;
  const int nb = (N + 1023) / 1024;

  char* ws = (char*)d_ws;
  size_t off = 0;
  auto alloc = [&](size_t bytes) -> void* {
    void* p = ws + off;
    off = (off + bytes + 255) & ~(size_t)255;
    return p;
  };
  // contiguous zero region: deg, bnA, bnB, bnC, done
  char* zbase = (char*)alloc(0);
  int*   deg   = (int*)  alloc((size_t)N * 4);
  float* bnA   = (float*)alloc(128 * 4);
  float* bnB   = (float*)alloc(128 * 4);
  float* bnC   = (float*)alloc(128 * 4);
  int*   done  = (int*)  alloc(4);
  size_t zbytes = (size_t)((char*)alloc(0) - zbase);
  int*   rowp  = (int*)  alloc((size_t)(N + 1) * 4);
  int*   fill  = (int*)  alloc((size_t)N * 4);
  int*   colv  = (int*)  alloc((size_t)(E + 16) * 4);       // +sentinel slot
  int*   dstv  = (int*)  alloc((size_t)E * 4);
  int*   bsum  = (int*)  alloc(64 * 4);
  float* dinv  = (float*)alloc((size_t)(N + 1) * 4);        // +sentinel node
  float* sdinv = (float*)alloc((size_t)N * 4);
  float* as1   = (float*)alloc((size_t)N * 4 * 4);
  float* ad1   = (float*)alloc((size_t)N * 4 * 4);
  float* as2ad2= (float*)alloc((size_t)(N + 1) * 2 * 4);    // +sentinel node
  float* aw2   = (float*)alloc(128 * 4);
  unsigned short* w4b = (unsigned short*)alloc((size_t)(E + 16) * 4 * 2); // +sentinel slot
  unsigned short* xh    = (unsigned short*)alloc((size_t)(N + 1) * 128 * 2);
  unsigned short* xl    = (unsigned short*)alloc((size_t)N * 128 * 2);
  unsigned short* gath  = (unsigned short*)alloc((size_t)(N + 1) * 256 * 2);
  unsigned short* oh    = (unsigned short*)alloc((size_t)N * 256 * 2);
  unsigned short* g1h   = (unsigned short*)alloc((size_t)(N + 1) * 64 * 2);
  unsigned short* g2h   = (unsigned short*)alloc((size_t)N * 64 * 2);
  unsigned short* aggXh = (unsigned short*)alloc((size_t)N * 128 * 2);
  unsigned short* aggSh = (unsigned short*)alloc((size_t)N * 64 * 2);
  unsigned short* m192  = (unsigned short*)alloc((size_t)(N + 1) * 192 * 2);
  unsigned short* cath  = (unsigned short*)alloc((size_t)N * 192 * 2);
  // weights
  unsigned short* b320h = (unsigned short*)alloc((size_t)320 * 128 * 2);
  unsigned short* b320l = (unsigned short*)alloc((size_t)320 * 128 * 2);
  unsigned short* gcn2h = (unsigned short*)alloc((size_t)64 * 64 * 2);
  unsigned short* gcn2l = (unsigned short*)alloc((size_t)64 * 64 * 2);
  unsigned short* gat2h = (unsigned short*)alloc((size_t)64 * 256 * 2);
  unsigned short* gat2l = (unsigned short*)alloc((size_t)64 * 256 * 2);
  unsigned short* s1wlh = (unsigned short*)alloc((size_t)64 * 128 * 2);
  unsigned short* s1wll = (unsigned short*)alloc((size_t)64 * 128 * 2);
  unsigned short* s1wrh = (unsigned short*)alloc((size_t)64 * 128 * 2);
  unsigned short* s1wrl = (unsigned short*)alloc((size_t)64 * 128 * 2);
  unsigned short* s2wlh = (unsigned short*)alloc((size_t)64 * 64 * 2);
  unsigned short* s2wll = (unsigned short*)alloc((size_t)64 * 64 * 2);
  unsigned short* s2wrh = (unsigned short*)alloc((size_t)64 * 64 * 2);
  unsigned short* s2wrl = (unsigned short*)alloc((size_t)64 * 64 * 2);
  unsigned short* fwh   = (unsigned short*)alloc((size_t)64 * 192 * 2);
  unsigned short* fwl   = (unsigned short*)alloc((size_t)64 * 192 * 2);
  float* fb             = (float*)alloc(64 * 4);

  hipMemsetAsync(zbase, 0, zbytes, stream);

  // CSR by destination + sentinel init
  k_count <<<(E + 255) / 256, 256, 0, stream>>>(dst, deg, E, N, gat2_as, gat2_ad, aw2,
                                                gath, xh, g1h, m192, colv, dinv, as2ad2);
  k_scan_a<<<nb, 256, 0, stream>>>(deg, bsum, N);
  k_scan_c<<<nb, 256, 0, stream>>>(deg, bsum, rowp, fill, dinv, sdinv, N, nb);
  k_scatter<<<(E + 255) / 256, 256, 0, stream>>>(src, dst, fill, colv, dstv, E);

  // weight splits + x split (one launch)
  {
    WPack p;
    p.d[0] = {gat1_w, b320h, b320l, 128, 256, 2};
    p.d[1] = {gcn1_w, b320h + 256 * 128, b320l + 256 * 128, 128, 64, 0};
    p.d[2] = {gat2_w, gat2h, gat2l, 256, 64, 1};
    p.d[3] = {sage1_wl, s1wlh, s1wll, 128, 64, 0};
    p.d[4] = {sage1_wr, s1wrh, s1wrl, 128, 64, 0};
    p.d[5] = {sage2_wl, s2wlh, s2wll, 64, 64, 0};
    p.d[6] = {sage2_wr, s2wrh, s2wrl, 64, 64, 0};
    p.d[7] = {gcn2_w, gcn2h, gcn2l, 64, 64, 0};
    p.d[8] = {x, xh, xl, N, 128, 3};
    dim3 g(1024, 9);
    k_wsplit<<<g, 256, 0, stream>>>(p);
  }

  const int gx = (N + 127) / 128;
  const int gn = (N + 3) / 4;

  // GAT1 + GCN1 fused GEMM (B = 320 cols)
  {
    dim3 g(gx, 5);
    k_gemm320<<<g, 256, 0, stream>>>(xh, xl, b320h, b320l, gath, g1h, N);
  }
  k_gat_attn4<<<gn, 256, 0, stream>>>(gath, gat1_as, gat1_ad, as1, ad1, N);
  k_edge_w4<<<(E + 255) / 256, 256, 0, stream>>>(colv, dstv, as1, ad1, w4b, E);
  // fused layer-1 aggregation (batch 16, sentinel)
  k_l1agg<<<gn, 256, 0, stream>>>(gath, xh, g1h, rowp, colv, w4b, as1, ad1,
                                  gat1_b, gcn1_b, dinv, sdinv, oh, g2h, aggXh, N, E);

  // batched GEMM: GAT2 (K=256, fused attn1 epilogue) | GCN2 | SAGE1 dual -> m192
  {
    BPack p;
    p.d[0] = {oh, nullptr, gat2h, gat2l, nullptr, nullptr, nullptr, nullptr,
              256, 256, 0, 0, nullptr, m192, 192, 0, 0, aw2, nullptr, as2ad2};
    p.d[1] = {g2h, nullptr, gcn2h, gcn2l, nullptr, nullptr, nullptr, nullptr,
              64, 64, 0, 0, nullptr, m192, 192, 64, 0, nullptr, nullptr, nullptr};
    p.d[2] = {aggXh, nullptr, s1wlh, s1wll, xh, xl, s1wrh, s1wrl,
              128, 128, 128, 128, sage1_bl, m192, 192, 128, 1, nullptr, nullptr, nullptr};
    dim3 g(gx, 3);
    k_gemm_b<<<g, 256, 0, stream>>>(p, N);
  }
  // F2 (sentinel, inline edge weights)
  k_f2<<<gn, 256, 0, stream>>>(m192, rowp, colv, as2ad2, dinv, sdinv,
                               gat2_b, gcn2_b, cath, aggSh, N, E);

  // SAGE2 dual GEMM -> cat cols 128-191
  {
    BPack p;
    p.d[0] = {aggSh, nullptr, s2wlh, s2wll, m192 + 128, nullptr, s2wrh, s2wrl,
              64, 64, 64, 192, sage2_bl, cath, 192, 128, 1, nullptr, nullptr, nullptr};
    p.d[1] = p.d[0]; p.d[2] = p.d[0];
    dim3 g(gx, 1);
    k_gemm_b<<<g, 256, 0, stream>>>(p, N);
  }

  // BN stats + last-block fold into fc1 weights
  {
    dim3 g(128, 3);
    k_bn_stats_fold<<<g, 256, 0, stream>>>(cath, bnB, bnA, bnC,
                                           bn_gcn_g, bn_gcn_b, bn_gat_g, bn_gat_b,
                                           bn_sage_g, bn_sage_b,
                                           fc1_w, fc1_b, (float)N, fwh, fwl, fb,
                                           done, 128 * 3, N);
  }

  // FC1 GEMM with fused 64->2 FC2 epilogue -> out
  {
    BPack p;
    p.d[0] = {cath, nullptr, fwh, fwl, nullptr, nullptr, nullptr, nullptr,
              192, 192, 0, 0, fb, nullptr, 64, 0, 1, fc2_w, fc2_b, out};
    p.d[1] = p.d[0]; p.d[2] = p.d[0];
    dim3 g(gx, 1);
    k_gemm_b<<<g, 256, 0, stream>>>(p, N);
  }
}

// Round 12
// 619.524 us; speedup vs baseline: 1.0169x; 1.0169x over previous
//
#include <hip/hip_runtime.h>
#include <math.h>

#define NEG_SLOPE 0.2f
#define BN_EPS 1e-5f

typedef short short8 __attribute__((ext_vector_type(8)));
typedef float floatx16 __attribute__((ext_vector_type(16)));

__device__ __forceinline__ float d_leaky(float x){ return x > 0.f ? x : NEG_SLOPE * x; }
__device__ __forceinline__ float d_elu(float x){ return x > 0.f ? x : expm1f(x); }

__device__ __forceinline__ unsigned short f2bf_rne(float f){
  unsigned int u = __float_as_uint(f);
  unsigned int r = (u + 0x7fffu + ((u >> 16) & 1u)) >> 16;
  return (unsigned short)r;
}
__device__ __forceinline__ float bf2f(unsigned short h){ return __uint_as_float((unsigned int)h << 16); }
__device__ __forceinline__ float2 bf2x(unsigned int u){
  float2 r;
  r.x = __uint_as_float(u << 16);
  r.y = __uint_as_float(u & 0xffff0000u);
  return r;
}

__device__ __forceinline__ float wave_sum(float v){
  #pragma unroll
  for (int off = 32; off > 0; off >>= 1) v += __shfl_xor(v, off, 64);
  return v;
}
__device__ __forceinline__ int wave_scan_incl(int v, int lane){
  #pragma unroll
  for (int off = 1; off < 64; off <<= 1){
    int u = __shfl_up(v, off, 64);
    if (lane >= off) v += u;
  }
  return v;
}

// ---------------- CSR build + sentinel init ----------------
__global__ void k_count(const int* __restrict__ dst, int* __restrict__ deg, int E, int N,
                        const float* __restrict__ g2as, const float* __restrict__ g2ad,
                        float* __restrict__ aw2,
                        unsigned short* __restrict__ gath, unsigned short* __restrict__ xh,
                        unsigned short* __restrict__ g1h, unsigned short* __restrict__ m192,
                        int* __restrict__ colv, float* __restrict__ dinv,
                        float* __restrict__ as2ad2){
  int e = blockIdx.x * blockDim.x + threadIdx.x;
  if (e < 64){ aw2[e * 2 + 0] = g2as[e]; aw2[e * 2 + 1] = g2ad[e]; }
  // sentinel node N: zero rows, zero dinv, -inf attention; sentinel edge E -> N
  if (e < 256) gath[(size_t)N * 256 + e] = 0;
  if (e < 128) xh[(size_t)N * 128 + e] = 0;
  if (e < 64)  g1h[(size_t)N * 64 + e] = 0;
  if (e < 192) m192[(size_t)N * 192 + e] = 0;
  if (e == 0){
    colv[E] = N;
    dinv[N] = 0.f;
    as2ad2[2 * N + 0] = -1e30f;
    as2ad2[2 * N + 1] = 0.f;
  }
  if (e < E) atomicAdd(&deg[dst[e]], 1);
}

__global__ __launch_bounds__(256) void k_scan_a(const int* __restrict__ deg, int* __restrict__ bsum, int n){
  int t = threadIdx.x;
  int base = blockIdx.x * 1024 + t * 4;
  int d0=0,d1=0,d2=0,d3=0;
  if (base + 3 < n){ int4 v = *(const int4*)(deg + base); d0=v.x; d1=v.y; d2=v.z; d3=v.w; }
  else {
    if (base   < n) d0 = deg[base];
    if (base+1 < n) d1 = deg[base+1];
    if (base+2 < n) d2 = deg[base+2];
    if (base+3 < n) d3 = deg[base+3];
  }
  int s = d0+d1+d2+d3;
  __shared__ int wsm[4];
  int lane = t & 63, w = t >> 6;
  int incl = wave_scan_incl(s, lane);
  if (lane == 63) wsm[w] = incl;
  __syncthreads();
  if (t == 0) bsum[blockIdx.x] = wsm[0]+wsm[1]+wsm[2]+wsm[3];
}

// scan_c with in-kernel block-prefix (bsum holds raw per-block sums; nb <= 64)
__global__ __launch_bounds__(256) void k_scan_c(const int* __restrict__ deg, const int* __restrict__ bsum,
                                                int* __restrict__ rowp, int* __restrict__ fill,
                                                float* __restrict__ dinv,
                                                float* __restrict__ sdinv, int n, int nb){
  __shared__ int sbx[2];
  int t = threadIdx.x;
  if (t < 64){
    int v = (t < nb) ? bsum[t] : 0;
    int incl = wave_scan_incl(v, t);
    if (t == (int)blockIdx.x) sbx[0] = incl - v;
    if (t == 63) sbx[1] = incl;
  }
  int base = blockIdx.x * 1024 + t * 4;
  int d0=0,d1=0,d2=0,d3=0;
  if (base + 3 < n){ int4 v = *(const int4*)(deg + base); d0=v.x; d1=v.y; d2=v.z; d3=v.w; }
  else {
    if (base   < n) d0 = deg[base];
    if (base+1 < n) d1 = deg[base+1];
    if (base+2 < n) d2 = deg[base+2];
    if (base+3 < n) d3 = deg[base+3];
  }
  int s = d0+d1+d2+d3;
  __shared__ int wsm[4];
  int lane = t & 63, w = t >> 6;
  int incl = wave_scan_incl(s, lane);
  if (lane == 63) wsm[w] = incl;
  __syncthreads();
  int woff = 0;
  #pragma unroll
  for (int j = 0; j < 4; j++) if (j < w) woff += wsm[j];
  int r = sbx[0] + woff + incl - s;
  int dd[4] = {d0,d1,d2,d3};
  #pragma unroll
  for (int j = 0; j < 4; j++){
    int i = base + j;
    if (i < n){
      rowp[i] = r;
      fill[i] = r;
      dinv[i] = rsqrtf((float)(dd[j] + 1));
      sdinv[i] = 1.0f / fmaxf((float)dd[j], 1.0f);
    }
    r += dd[j];
  }
  if (blockIdx.x == 0 && t == 0) rowp[n] = sbx[1];
}

__global__ void k_scatter(const int* __restrict__ src, const int* __restrict__ dst,
                          int* __restrict__ fill,
                          int* __restrict__ colv, int* __restrict__ dstv, int E){
  int e = blockIdx.x * blockDim.x + threadIdx.x;
  if (e < E){
    int d = dst[e];
    int pos = atomicAdd(&fill[d], 1);
    colv[pos] = src[e];
    dstv[pos] = d;
  }
}

// ---------------- weight transpose + split (+ x-split as perm 3) ----------------
struct WDesc { const float* w; unsigned short* th; unsigned short* tl; int K; int Nc; int perm; };
struct WPack { WDesc d[9]; };
__global__ void k_wsplit(WPack p){
  WDesc w = p.d[blockIdx.y];
  int total = w.K * w.Nc;
  if (w.perm == 3){
    for (int i = blockIdx.x * blockDim.x + threadIdx.x; i < total; i += gridDim.x * blockDim.x){
      float v = w.w[i];
      unsigned short h = f2bf_rne(v);
      w.th[i] = h;
      w.tl[i] = f2bf_rne(v - bf2f(h));
    }
    return;
  }
  for (int i = blockIdx.x * blockDim.x + threadIdx.x; i < total; i += gridDim.x * blockDim.x){
    int k = i / w.Nc, n = i % w.Nc;
    int kd = (w.perm == 1) ? ((k & 63) * 4 + (k >> 6)) : k;
    int nd = (w.perm == 2) ? (((n & 63) << 2) | (n >> 6)) : n;
    float v = w.w[i];
    unsigned short h = f2bf_rne(v);
    w.th[(size_t)nd * w.K + kd] = h;
    w.tl[(size_t)nd * w.K + kd] = f2bf_rne(v - bf2f(h));
  }
}

// ---------------- GEMM term helper ----------------
__device__ __forceinline__ void gemm_term(floatx16& acc0, floatx16& acc1,
    const unsigned short* __restrict__ Ah, const unsigned short* __restrict__ Al,
    const unsigned short* __restrict__ Bh, const unsigned short* __restrict__ Bl,
    int K, int lda, int arow, int lr, int ko8){
  const unsigned short* ap  = Ah + (size_t)arow * lda + ko8;
  const unsigned short* alp = Al ? Al + (size_t)arow * lda + ko8 : nullptr;
  const unsigned short* bh0 = Bh + (size_t)lr * K + ko8;
  const unsigned short* bl0 = Bl + (size_t)lr * K + ko8;
  const unsigned short* bh1 = bh0 + (size_t)32 * K;
  const unsigned short* bl1 = bl0 + (size_t)32 * K;
  for (int k0 = 0; k0 < K; k0 += 16){
    short8 a  = *(const short8*)(ap + k0);
    short8 h0 = *(const short8*)(bh0 + k0);
    short8 l0 = *(const short8*)(bl0 + k0);
    short8 h1 = *(const short8*)(bh1 + k0);
    short8 l1 = *(const short8*)(bl1 + k0);
    if (alp){
      short8 a2 = *(const short8*)(alp + k0);
      acc0 = __builtin_amdgcn_mfma_f32_32x32x16_bf16(a2, h0, acc0, 0, 0, 0);
      acc1 = __builtin_amdgcn_mfma_f32_32x32x16_bf16(a2, h1, acc1, 0, 0, 0);
    }
    acc0 = __builtin_amdgcn_mfma_f32_32x32x16_bf16(a, l0, acc0, 0, 0, 0);
    acc0 = __builtin_amdgcn_mfma_f32_32x32x16_bf16(a, h0, acc0, 0, 0, 0);
    acc1 = __builtin_amdgcn_mfma_f32_32x32x16_bf16(a, l1, acc1, 0, 0, 0);
    acc1 = __builtin_amdgcn_mfma_f32_32x32x16_bf16(a, h1, acc1, 0, 0, 0);
  }
}

// ---------------- batched MFMA GEMM ----------------
struct BDesc {
  const unsigned short *A1h, *A1l, *B1h, *B1l;
  const unsigned short *A2h, *A2l, *B2h, *B2l;
  int K1, lda1, K2, lda2;
  const float* bias;
  unsigned short* out; int ldc, coloff, act;
  const float* fc2w; const float* fc2b; float* outf;
};
struct BPack { BDesc d[3]; };
__global__ __launch_bounds__(256) void k_gemm_b(BPack p, int M){
  BDesc d = p.d[blockIdx.y];
  int wave = threadIdx.x >> 6, lane = threadIdx.x & 63;
  int m0 = blockIdx.x * 128 + wave * 32;
  int lr = lane & 31;
  int ko8 = (lane >> 5) * 8;
  floatx16 acc0 = {0,0,0,0,0,0,0,0,0,0,0,0,0,0,0,0};
  floatx16 acc1 = {0,0,0,0,0,0,0,0,0,0,0,0,0,0,0,0};
  int arow = m0 + lr; if (arow >= M) arow = M - 1;
  gemm_term(acc0, acc1, d.A1h, d.A1l, d.B1h, d.B1l, d.K1, d.lda1, arow, lr, ko8);
  if (d.K2) gemm_term(acc0, acc1, d.A2h, d.A2l, d.B2h, d.B2l, d.K2, d.lda2, arow, lr, ko8);
  int col0 = lr, col1 = lr + 32;
  float bias0 = d.bias ? d.bias[col0] : 0.f;
  float bias1 = d.bias ? d.bias[col1] : 0.f;
  float w00 = 0.f, w01 = 0.f, w10 = 0.f, w11 = 0.f, fb0 = 0.f, fb1 = 0.f;
  if (d.fc2w){
    w00 = d.fc2w[col0 * 2 + 0]; w01 = d.fc2w[col0 * 2 + 1];
    w10 = d.fc2w[col1 * 2 + 0]; w11 = d.fc2w[col1 * 2 + 1];
    if (d.fc2b){ fb0 = d.fc2b[0]; fb1 = d.fc2b[1]; }
  }
  int rbase = m0 + 4 * (lane >> 5);
  #pragma unroll
  for (int reg = 0; reg < 16; reg++){
    int row = rbase + (reg & 3) + 8 * (reg >> 2);
    float v0 = acc0[reg] + bias0;
    float v1 = acc1[reg] + bias1;
    if (d.act){ v0 = fmaxf(v0, 0.f); v1 = fmaxf(v1, 0.f); }
    if (d.out && row < M){
      d.out[(size_t)row * d.ldc + d.coloff + col0] = f2bf_rne(v0);
      d.out[(size_t)row * d.ldc + d.coloff + col1] = f2bf_rne(v1);
    }
    if (d.fc2w){
      float p0 = v0 * w00 + v1 * w10;
      float p1 = v0 * w01 + v1 * w11;
      #pragma unroll
      for (int off = 16; off > 0; off >>= 1){
        p0 += __shfl_xor(p0, off, 64);
        p1 += __shfl_xor(p1, off, 64);
      }
      if ((lane & 31) == 0 && row < M){
        d.outf[(size_t)row * 2 + 0] = p0 + fb0;
        d.outf[(size_t)row * 2 + 1] = p1 + fb1;
      }
    }
  }
}

// ---------------- GEMM320 ----------------
__global__ __launch_bounds__(256) void k_gemm320(
    const unsigned short* __restrict__ Ah, const unsigned short* __restrict__ Al,
    const unsigned short* __restrict__ Bh, const unsigned short* __restrict__ Bl,
    unsigned short* __restrict__ C1, unsigned short* __restrict__ C2, int M)
{
  const int K = 128;
  int wave = threadIdx.x >> 6, lane = threadIdx.x & 63;
  int m0 = blockIdx.x * 128 + wave * 32;
  int n0 = blockIdx.y * 64;
  int lr = lane & 31;
  int ko8 = (lane >> 5) * 8;
  floatx16 acc0 = {0,0,0,0,0,0,0,0,0,0,0,0,0,0,0,0};
  floatx16 acc1 = {0,0,0,0,0,0,0,0,0,0,0,0,0,0,0,0};
  int arow = m0 + lr; if (arow >= M) arow = M - 1;
  const unsigned short* ap_h = Ah + (size_t)arow * K + ko8;
  const unsigned short* ap_l = Al + (size_t)arow * K + ko8;
  const unsigned short* bp_h0 = Bh + (size_t)(n0 + lr) * K + ko8;
  const unsigned short* bp_l0 = Bl + (size_t)(n0 + lr) * K + ko8;
  const unsigned short* bp_h1 = bp_h0 + (size_t)32 * K;
  const unsigned short* bp_l1 = bp_l0 + (size_t)32 * K;
  for (int k0 = 0; k0 < K; k0 += 16){
    short8 a_h  = *(const short8*)(ap_h + k0);
    short8 a_l  = *(const short8*)(ap_l + k0);
    short8 b_h0 = *(const short8*)(bp_h0 + k0);
    short8 b_l0 = *(const short8*)(bp_l0 + k0);
    short8 b_h1 = *(const short8*)(bp_h1 + k0);
    short8 b_l1 = *(const short8*)(bp_l1 + k0);
    acc0 = __builtin_amdgcn_mfma_f32_32x32x16_bf16(a_l, b_h0, acc0, 0, 0, 0);
    acc0 = __builtin_amdgcn_mfma_f32_32x32x16_bf16(a_h, b_l0, acc0, 0, 0, 0);
    acc0 = __builtin_amdgcn_mfma_f32_32x32x16_bf16(a_h, b_h0, acc0, 0, 0, 0);
    acc1 = __builtin_amdgcn_mfma_f32_32x32x16_bf16(a_l, b_h1, acc1, 0, 0, 0);
    acc1 = __builtin_amdgcn_mfma_f32_32x32x16_bf16(a_h, b_l1, acc1, 0, 0, 0);
    acc1 = __builtin_amdgcn_mfma_f32_32x32x16_bf16(a_h, b_h1, acc1, 0, 0, 0);
  }
  int col0 = n0 + lr, col1 = col0 + 32;
  unsigned short* Cp; int ld, c0, c1;
  if (col0 >= 256){ Cp = C2; ld = 64; c0 = col0 - 256; c1 = col1 - 256; }
  else { Cp = C1; ld = 256; c0 = col0; c1 = col1; }
  int rbase = m0 + 4 * (lane >> 5);
  #pragma unroll
  for (int reg = 0; reg < 16; reg++){
    int row = rbase + (reg & 3) + 8 * (reg >> 2);
    if (row >= M) continue;
    Cp[(size_t)row * ld + c0] = f2bf_rne(acc0[reg]);
    Cp[(size_t)row * ld + c1] = f2bf_rne(acc1[reg]);
  }
}

// ---------------- GAT1 attention coeffs ----------------
__global__ __launch_bounds__(256) void k_gat_attn4(
    const unsigned short* __restrict__ h, const float* __restrict__ asrc,
    const float* __restrict__ adst, float* __restrict__ a_s, float* __restrict__ a_d, int n){
  int node = blockIdx.x * 4 + (threadIdx.x >> 6);
  int c = threadIdx.x & 63;
  if (node >= n) return;
  uint2 u = *(const uint2*)(h + (size_t)node * 256 + c * 4);
  float2 p0 = bf2x(u.x), p1 = bf2x(u.y);
  float s0 = wave_sum(p0.x * asrc[c]);
  float s1 = wave_sum(p0.y * asrc[64 + c]);
  float s2 = wave_sum(p1.x * asrc[128 + c]);
  float s3 = wave_sum(p1.y * asrc[192 + c]);
  float d0 = wave_sum(p0.x * adst[c]);
  float d1 = wave_sum(p0.y * adst[64 + c]);
  float d2 = wave_sum(p1.x * adst[128 + c]);
  float d3 = wave_sum(p1.y * adst[192 + c]);
  if (c == 0){
    *(float4*)(a_s + (size_t)node * 4) = make_float4(s0, s1, s2, s3);
    *(float4*)(a_d + (size_t)node * 4) = make_float4(d0, d1, d2, d3);
  }
}

// ---------------- per-edge softmax numerators (layer 1, packed bf16) ----------------
__global__ void k_edge_w4(const int* __restrict__ colv, const int* __restrict__ dstv,
                          const float* __restrict__ a_s, const float* __restrict__ a_d,
                          unsigned short* __restrict__ w4b, int E){
  int i = blockIdx.x * blockDim.x + threadIdx.x;
  if (i == 0){
    *(uint2*)(w4b + (size_t)E * 4) = make_uint2(0u, 0u);  // sentinel edge: zero weights
  }
  if (i >= E) return;
  float4 s4 = *(const float4*)(a_s + (size_t)colv[i] * 4);
  float4 d4 = *(const float4*)(a_d + (size_t)dstv[i] * 4);
  float w0 = __expf(d_leaky(s4.x + d4.x));
  float w1 = __expf(d_leaky(s4.y + d4.y));
  float w2 = __expf(d_leaky(s4.z + d4.z));
  float w3 = __expf(d_leaky(s4.w + d4.w));
  uint2 q;
  q.x = (unsigned int)f2bf_rne(w0) | ((unsigned int)f2bf_rne(w1) << 16);
  q.y = (unsigned int)f2bf_rne(w2) | ((unsigned int)f2bf_rne(w3) << 16);
  *(uint2*)(w4b + (size_t)i * 4) = q;
}

// ---------------- L1AGG: fused GAT1 + GCN1 + SAGE-x aggregation, batch 8, sentinel ----------------
__global__ __launch_bounds__(256) void k_l1agg(
    const unsigned short* __restrict__ gath, const unsigned short* __restrict__ xh,
    const unsigned short* __restrict__ g1h,
    const int* __restrict__ rowp, const int* __restrict__ colv,
    const unsigned short* __restrict__ w4b,
    const float* __restrict__ a_s, const float* __restrict__ a_d,
    const float* __restrict__ gat1_b, const float* __restrict__ gcn1_b,
    const float* __restrict__ dinv, const float* __restrict__ sdinv,
    unsigned short* __restrict__ oh, unsigned short* __restrict__ g2h,
    unsigned short* __restrict__ aggXh, int n, int Esent)
{
  int node = blockIdx.x * 4 + (threadIdx.x >> 6);
  int c = threadIdx.x & 63;
  if (node >= n) return;
  float4 asn = *(const float4*)(a_s + (size_t)node * 4);
  float4 adn = *(const float4*)(a_d + (size_t)node * 4);
  float ws0 = __expf(d_leaky(asn.x + adn.x));
  float ws1 = __expf(d_leaky(asn.y + adn.y));
  float ws2 = __expf(d_leaky(asn.z + adn.z));
  float ws3 = __expf(d_leaky(asn.w + adn.w));
  uint2 su = *(const uint2*)(gath + (size_t)node * 256 + c * 4);
  float2 sp0 = bf2x(su.x), sp1 = bf2x(su.y);
  float den0 = ws0, den1 = ws1, den2 = ws2, den3 = ws3;
  float acc0 = ws0 * sp0.x, acc1 = ws1 * sp0.y, acc2 = ws2 * sp1.x, acc3 = ws3 * sp1.y;
  float di = dinv[node];
  float gacc = di * bf2f(g1h[(size_t)node * 64 + c]);
  float sx0 = 0.f, sx1 = 0.f;
  int b = rowp[node], e = rowp[node + 1];
  for (int i = b; i < e; i += 8){
    int s[8];
    #pragma unroll
    for (int j = 0; j < 8; j++){
      int t = i + j;
      s[j] = (t < e) ? t : Esent;
    }
    uint2 wq[8];
    #pragma unroll
    for (int j = 0; j < 8; j++) wq[j] = *(const uint2*)(w4b + (size_t)s[j] * 4);
    #pragma unroll
    for (int j = 0; j < 8; j++) s[j] = colv[s[j]];
    uint2 hv[8];
    #pragma unroll
    for (int j = 0; j < 8; j++) hv[j] = *(const uint2*)(gath + (size_t)s[j] * 256 + c * 4);
    unsigned int hx[8];
    #pragma unroll
    for (int j = 0; j < 8; j++) hx[j] = *(const unsigned int*)(xh + (size_t)s[j] * 128 + c * 2);
    unsigned short hg[8];
    #pragma unroll
    for (int j = 0; j < 8; j++) hg[j] = g1h[(size_t)s[j] * 64 + c];
    float wd[8];
    #pragma unroll
    for (int j = 0; j < 8; j++) wd[j] = dinv[s[j]];
    #pragma unroll
    for (int j = 0; j < 8; j++){
      float2 w01 = bf2x(wq[j].x), w23 = bf2x(wq[j].y);
      float2 a = bf2x(hv[j].x), bb = bf2x(hv[j].y);
      den0 += w01.x; den1 += w01.y; den2 += w23.x; den3 += w23.y;
      acc0 += w01.x * a.x;  acc1 += w01.y * a.y;
      acc2 += w23.x * bb.x; acc3 += w23.y * bb.y;
      gacc += wd[j] * bf2f(hg[j]);
      float2 p = bf2x(hx[j]);
      sx0 += p.x; sx1 += p.y;
    }
  }
  float v0 = d_elu(acc0 / (den0 + 1e-16f) + gat1_b[c]);
  float v1 = d_elu(acc1 / (den1 + 1e-16f) + gat1_b[64 + c]);
  float v2 = d_elu(acc2 / (den2 + 1e-16f) + gat1_b[128 + c]);
  float v3 = d_elu(acc3 / (den3 + 1e-16f) + gat1_b[192 + c]);
  uint2 ohv;
  ohv.x = (unsigned int)f2bf_rne(v0) | ((unsigned int)f2bf_rne(v1) << 16);
  ohv.y = (unsigned int)f2bf_rne(v2) | ((unsigned int)f2bf_rne(v3) << 16);
  *(uint2*)(oh + (size_t)node * 256 + c * 4) = ohv;
  g2h[(size_t)node * 64 + c] = f2bf_rne(fmaxf(di * gacc + gcn1_b[c], 0.f));
  float sd = sdinv[node];
  *(unsigned int*)(aggXh + (size_t)node * 128 + c * 2) =
      (unsigned int)f2bf_rne(sx0 * sd) | ((unsigned int)f2bf_rne(sx1 * sd) << 16);
}

// ---------------- F2: fused GAT2 + GCN2 + SAGE-s1 aggregation, batch 8, sentinel ----------------
__global__ __launch_bounds__(256) void k_f2(
    const unsigned short* __restrict__ m192,
    const int* __restrict__ rowp, const int* __restrict__ colv,
    const float* __restrict__ as2ad2,
    const float* __restrict__ dinv, const float* __restrict__ sdinv,
    const float* __restrict__ gat2_b, const float* __restrict__ gcn2_b,
    unsigned short* __restrict__ cat, unsigned short* __restrict__ aggSh,
    int n, int Esent){
  int node = blockIdx.x * 4 + (threadIdx.x >> 6);
  int c = threadIdx.x & 63;
  if (node >= n) return;
  float di = dinv[node];
  const unsigned short* srow = m192 + (size_t)node * 192;
  float adn = as2ad2[node * 2 + 1];
  float tden = __expf(d_leaky(as2ad2[node * 2 + 0] + adn));
  float tacc = tden * bf2f(srow[c]);
  float gacc = di * bf2f(srow[64 + c]);
  float sacc = 0.f;
  int b = rowp[node], e = rowp[node + 1];
  for (int i = b; i < e; i += 8){
    int s[8];
    #pragma unroll
    for (int j = 0; j < 8; j++){
      int t = i + j;
      s[j] = colv[(t < e) ? t : Esent];
    }
    float w[8];
    #pragma unroll
    for (int j = 0; j < 8; j++) w[j] = __expf(d_leaky(as2ad2[(size_t)s[j] * 2] + adn));
    unsigned short ht[8], hg[8], hs[8];
    #pragma unroll
    for (int j = 0; j < 8; j++){
      const unsigned short* r = m192 + (size_t)s[j] * 192;
      ht[j] = r[c]; hg[j] = r[64 + c]; hs[j] = r[128 + c];
    }
    float wd[8];
    #pragma unroll
    for (int j = 0; j < 8; j++) wd[j] = dinv[s[j]];
    #pragma unroll
    for (int j = 0; j < 8; j++){
      tden += w[j]; tacc += w[j] * bf2f(ht[j]);
      gacc += wd[j] * bf2f(hg[j]);
      sacc += bf2f(hs[j]);
    }
  }
  cat[(size_t)node * 192 + 64 + c] = f2bf_rne(d_elu(tacc / (tden + 1e-16f) + gat2_b[c]));
  cat[(size_t)node * 192 + c] = f2bf_rne(fmaxf(di * gacc + gcn2_b[c], 0.f));
  aggSh[(size_t)node * 64 + c] = f2bf_rne(sacc * sdinv[node]);
}

// ---------------- BN stats + last-block BN-fold into fc1 weights ----------------
__global__ __launch_bounds__(256) void k_bn_stats_fold(
    const unsigned short* __restrict__ x,
    float* __restrict__ bnGCN, float* __restrict__ bnGAT, float* __restrict__ bnSAGE,
    const float* __restrict__ gg, const float* __restrict__ gb,
    const float* __restrict__ ag, const float* __restrict__ ab,
    const float* __restrict__ sg, const float* __restrict__ sb,
    const float* __restrict__ w, const float* __restrict__ wb, float nf,
    unsigned short* __restrict__ fwh, unsigned short* __restrict__ fwl, float* __restrict__ fb,
    int* __restrict__ done, int nblocks, int n)
{
  int seg = blockIdx.y;
  float* sums = (seg == 0) ? bnGCN : (seg == 1) ? bnGAT : bnSAGE;
  int co = seg * 64;
  int c = threadIdx.x & 63;
  int rl = threadIdx.x >> 6;
  float s = 0.f, q = 0.f;
  for (int r = blockIdx.x * 4 + rl; r < n; r += gridDim.x * 4){
    float v = bf2f(x[(size_t)r * 192 + co + c]);
    s += v; q += v * v;
  }
  __shared__ float ls[4][64], lq[4][64];
  ls[rl][c] = s; lq[rl][c] = q;
  __syncthreads();
  if (rl == 0){
    s = ls[0][c] + ls[1][c] + ls[2][c] + ls[3][c];
    q = lq[0][c] + lq[1][c] + lq[2][c] + lq[3][c];
    atomicAdd(&sums[c], s);
    atomicAdd(&sums[64 + c], q);
  }
  __syncthreads();
  __shared__ int lastflag;
  if (threadIdx.x == 0){
    __threadfence();
    int old = atomicAdd(done, 1);
    lastflag = (old == nblocks - 1);
  }
  __syncthreads();
  if (!lastflag) return;
  __threadfence();
  __shared__ float sbn[3][128];
  for (int i = threadIdx.x; i < 384; i += 256){
    float* p = (i < 128) ? bnGCN : (i < 256) ? bnGAT : bnSAGE;
    sbn[i >> 7][i & 127] = atomicAdd(&p[i & 127], 0.0f);
  }
  __syncthreads();
  int tid = threadIdx.x;
  auto st = [&](int c2, float& sc, float& tc){
    int cc = c2 & 63;
    int sg2 = c2 >> 6;
    const float *g, *b;
    if (sg2 == 0){ g = gg; b = gb; }
    else if (sg2 == 1){ g = ag; b = ab; }
    else { g = sg; b = sb; }
    float m = sbn[sg2][cc] / nf;
    float var = sbn[sg2][64 + cc] / nf - m * m;
    float inv = rsqrtf(var + BN_EPS);
    sc = inv * g[cc];
    tc = b[cc] - m * inv * g[cc];
  };
  if (tid < 64){
    float acc = wb[tid];
    for (int c2 = 0; c2 < 192; c2++){
      float sc, tc; st(c2, sc, tc);
      acc += tc * w[c2 * 64 + tid];
    }
    fb[tid] = acc;
  }
  for (int i = tid; i < 192 * 64; i += 256){
    int c2 = i >> 6, nn = i & 63;
    float sc, tc; st(c2, sc, tc);
    float v = sc * w[i];
    unsigned short hh = f2bf_rne(v);
    fwh[nn * 192 + c2] = hh;
    fwl[nn * 192 + c2] = f2bf_rne(v - bf2f(hh));
  }
}

extern "C" void kernel_launch(void* const* d_in, const int* in_sizes, int n_in,
                              void* d_out, int out_size, void* d_ws, size_t ws_size,
                              hipStream_t stream){
  (void)n_in; (void)out_size; (void)ws_size;
  const float* x        = (const float*)d_in[0];
  const int*   ei       = (const int*)  d_in[1];
  const float* gcn1_w   = (const float*)d_in[2];
  const float* gcn1_b   = (const float*)d_in[3];
  const float* gcn2_w   = (const float*)d_in[4];
  const float* gcn2_b   = (const float*)d_in[5];
  const float* gat1_w   = (const float*)d_in[6];
  const float* gat1_as  = (const float*)d_in[7];
  const float* gat1_ad  = (const float*)d_in[8];
  const float* gat1_b   = (const float*)d_in[9];
  const float* gat2_w   = (const float*)d_in[10];
  const float* gat2_as  = (const float*)d_in[11];
  const float* gat2_ad  = (const float*)d_in[12];
  const float* gat2_b   = (const float*)d_in[13];
  const float* sage1_wl = (const float*)d_in[14];
  const float* sage1_bl = (const float*)d_in[15];
  const float* sage1_wr = (const float*)d_in[16];
  const float* sage2_wl = (const float*)d_in[17];
  const float* sage2_bl = (const float*)d_in[18];
  const float* sage2_wr = (const float*)d_in[19];
  const float* bn_gcn_g = (const float*)d_in[20];
  const float* bn_gcn_b = (const float*)d_in[21];
  const float* bn_gat_g = (const float*)d_in[22];
  const float* bn_gat_b = (const float*)d_in[23];
  const float* bn_sage_g= (const float*)d_in[24];
  const float* bn_sage_b= (const float*)d_in[25];
  const float* fc1_w    = (const float*)d_in[26];
  const float* fc1_b    = (const float*)d_in[27];
  const float* fc2_w    = (const float*)d_in[28];
  const float* fc2_b    = (const float*)d_in[29];
  float* out = (float*)d_out;

  const int N = in_sizes[0] / 128;
  const int E = in_sizes[1] / 2;
  const int* src = ei;
  const int* dst = ei + E;
  const int nb = (N + 1023) / 1024;

  char* ws = (char*)d_ws;
  size_t off = 0;
  auto alloc = [&](size_t bytes) -> void* {
    void* p = ws + off;
    off = (off + bytes + 255) & ~(size_t)255;
    return p;
  };
  // contiguous zero region: deg, bnA, bnB, bnC, done
  char* zbase = (char*)alloc(0);
  int*   deg   = (int*)  alloc((size_t)N * 4);
  float* bnA   = (float*)alloc(128 * 4);
  float* bnB   = (float*)alloc(128 * 4);
  float* bnC   = (float*)alloc(128 * 4);
  int*   done  = (int*)  alloc(4);
  size_t zbytes = (size_t)((char*)alloc(0) - zbase);
  int*   rowp  = (int*)  alloc((size_t)(N + 1) * 4);
  int*   fill  = (int*)  alloc((size_t)N * 4);
  int*   colv  = (int*)  alloc((size_t)(E + 16) * 4);
  int*   dstv  = (int*)  alloc((size_t)E * 4);
  int*   bsum  = (int*)  alloc(64 * 4);
  float* dinv  = (float*)alloc((size_t)(N + 1) * 4);
  float* sdinv = (float*)alloc((size_t)N * 4);
  float* as1   = (float*)alloc((size_t)N * 4 * 4);
  float* ad1   = (float*)alloc((size_t)N * 4 * 4);
  float* as2ad2= (float*)alloc((size_t)(N + 1) * 2 * 4);
  float* aw2   = (float*)alloc(128 * 4);
  unsigned short* w4b = (unsigned short*)alloc((size_t)(E + 16) * 4 * 2);
  unsigned short* xh    = (unsigned short*)alloc((size_t)(N + 1) * 128 * 2);
  unsigned short* xl    = (unsigned short*)alloc((size_t)N * 128 * 2);
  unsigned short* gath  = (unsigned short*)alloc((size_t)(N + 1) * 256 * 2);
  unsigned short* oh    = (unsigned short*)alloc((size_t)N * 256 * 2);
  unsigned short* g1h   = (unsigned short*)alloc((size_t)(N + 1) * 64 * 2);
  unsigned short* g2h   = (unsigned short*)alloc((size_t)N * 64 * 2);
  unsigned short* aggXh = (unsigned short*)alloc((size_t)N * 128 * 2);
  unsigned short* aggSh = (unsigned short*)alloc((size_t)N * 64 * 2);
  unsigned short* m192  = (unsigned short*)alloc((size_t)(N + 1) * 192 * 2);
  unsigned short* cath  = (unsigned short*)alloc((size_t)N * 192 * 2);
  // weights
  unsigned short* b320h = (unsigned short*)alloc((size_t)320 * 128 * 2);
  unsigned short* b320l = (unsigned short*)alloc((size_t)320 * 128 * 2);
  unsigned short* gcn2h = (unsigned short*)alloc((size_t)64 * 64 * 2);
  unsigned short* gcn2l = (unsigned short*)alloc((size_t)64 * 64 * 2);
  unsigned short* gat2h = (unsigned short*)alloc((size_t)64 * 256 * 2);
  unsigned short* gat2l = (unsigned short*)alloc((size_t)64 * 256 * 2);
  unsigned short* s1wlh = (unsigned short*)alloc((size_t)64 * 128 * 2);
  unsigned short* s1wll = (unsigned short*)alloc((size_t)64 * 128 * 2);
  unsigned short* s1wrh = (unsigned short*)alloc((size_t)64 * 128 * 2);
  unsigned short* s1wrl = (unsigned short*)alloc((size_t)64 * 128 * 2);
  unsigned short* s2wlh = (unsigned short*)alloc((size_t)64 * 64 * 2);
  unsigned short* s2wll = (unsigned short*)alloc((size_t)64 * 64 * 2);
  unsigned short* s2wrh = (unsigned short*)alloc((size_t)64 * 64 * 2);
  unsigned short* s2wrl = (unsigned short*)alloc((size_t)64 * 64 * 2);
  unsigned short* fwh   = (unsigned short*)alloc((size_t)64 * 192 * 2);
  unsigned short* fwl   = (unsigned short*)alloc((size_t)64 * 192 * 2);
  float* fb             = (float*)alloc(64 * 4);

  hipMemsetAsync(zbase, 0, zbytes, stream);

  // CSR by destination + sentinel init
  k_count <<<(E + 255) / 256, 256, 0, stream>>>(dst, deg, E, N, gat2_as, gat2_ad, aw2,
                                                gath, xh, g1h, m192, colv, dinv, as2ad2);
  k_scan_a<<<nb, 256, 0, stream>>>(deg, bsum, N);
  k_scan_c<<<nb, 256, 0, stream>>>(deg, bsum, rowp, fill, dinv, sdinv, N, nb);
  k_scatter<<<(E + 255) / 256, 256, 0, stream>>>(src, dst, fill, colv, dstv, E);

  // weight splits + x split (one launch)
  {
    WPack p;
    p.d[0] = {gat1_w, b320h, b320l, 128, 256, 2};
    p.d[1] = {gcn1_w, b320h + 256 * 128, b320l + 256 * 128, 128, 64, 0};
    p.d[2] = {gat2_w, gat2h, gat2l, 256, 64, 1};
    p.d[3] = {sage1_wl, s1wlh, s1wll, 128, 64, 0};
    p.d[4] = {sage1_wr, s1wrh, s1wrl, 128, 64, 0};
    p.d[5] = {sage2_wl, s2wlh, s2wll, 64, 64, 0};
    p.d[6] = {sage2_wr, s2wrh, s2wrl, 64, 64, 0};
    p.d[7] = {gcn2_w, gcn2h, gcn2l, 64, 64, 0};
    p.d[8] = {x, xh, xl, N, 128, 3};
    dim3 g(1024, 9);
    k_wsplit<<<g, 256, 0, stream>>>(p);
  }

  const int gx = (N + 127) / 128;
  const int gn = (N + 3) / 4;

  // GAT1 + GCN1 fused GEMM (B = 320 cols)
  {
    dim3 g(gx, 5);
    k_gemm320<<<g, 256, 0, stream>>>(xh, xl, b320h, b320l, gath, g1h, N);
  }
  k_gat_attn4<<<gn, 256, 0, stream>>>(gath, gat1_as, gat1_ad, as1, ad1, N);
  k_edge_w4<<<(E + 255) / 256, 256, 0, stream>>>(colv, dstv, as1, ad1, w4b, E);
  // fused layer-1 aggregation (batch 8, sentinel)
  k_l1agg<<<gn, 256, 0, stream>>>(gath, xh, g1h, rowp, colv, w4b, as1, ad1,
                                  gat1_b, gcn1_b, dinv, sdinv, oh, g2h, aggXh, N, E);

  // batched GEMM: GAT2 (K=256, fused attn1 epilogue) | GCN2 | SAGE1 dual -> m192
  {
    BPack p;
    p.d[0] = {oh, nullptr, gat2h, gat2l, nullptr, nullptr, nullptr, nullptr,
              256, 256, 0, 0, nullptr, m192, 192, 0, 0, aw2, nullptr, as2ad2};
    p.d[1] = {g2h, nullptr, gcn2h, gcn2l, nullptr, nullptr, nullptr, nullptr,
              64, 64, 0, 0, nullptr, m192, 192, 64, 0, nullptr, nullptr, nullptr};
    p.d[2] = {aggXh, nullptr, s1wlh, s1wll, xh, xl, s1wrh, s1wrl,
              128, 128, 128, 128, sage1_bl, m192, 192, 128, 1, nullptr, nullptr, nullptr};
    dim3 g(gx, 3);
    k_gemm_b<<<g, 256, 0, stream>>>(p, N);
  }
  // F2 (sentinel, inline edge weights)
  k_f2<<<gn, 256, 0, stream>>>(m192, rowp, colv, as2ad2, dinv, sdinv,
                               gat2_b, gcn2_b, cath, aggSh, N, E);

  // SAGE2 dual GEMM -> cat cols 128-191
  {
    BPack p;
    p.d[0] = {aggSh, nullptr, s2wlh, s2wll, m192 + 128, nullptr, s2wrh, s2wrl,
              64, 64, 64, 192, sage2_bl, cath, 192, 128, 1, nullptr, nullptr, nullptr};
    p.d[1] = p.d[0]; p.d[2] = p.d[0];
    dim3 g(gx, 1);
    k_gemm_b<<<g, 256, 0, stream>>>(p, N);
  }

  // BN stats + last-block fold into fc1 weights
  {
    dim3 g(128, 3);
    k_bn_stats_fold<<<g, 256, 0, stream>>>(cath, bnB, bnA, bnC,
                                           bn_gcn_g, bn_gcn_b, bn_gat_g, bn_gat_b,
                                           bn_sage_g, bn_sage_b,
                                           fc1_w, fc1_b, (float)N, fwh, fwl, fb,
                                           done, 128 * 3, N);
  }

  // FC1 GEMM with fused 64->2 FC2 epilogue -> out
  {
    BPack p;
    p.d[0] = {cath, nullptr, fwh, fwl, nullptr, nullptr, nullptr, nullptr,
              192, 192, 0, 0, fb, nullptr, 64, 0, 1, fc2_w, fc2_b, out};
    p.d[1] = p.d[0]; p.d[2] = p.d[0];
    dim3 g(gx, 1);
    k_gemm_b<<<g, 256, 0, stream>>>(p, N);
  }
}